// Round 5
// baseline (336.173 us; speedup 1.0000x reference)
//
#include <hip/hip_runtime.h>
#include <hip/hip_fp16.h>

#define D 128
#define SCAN_B 256
#define R 8  // degree-counter replicas (contention spreading)

// ---------------- replicated degree + rank: rank[e] = degR[r][dst[e]]++ -------
// r = blockIdx & 7 — MUST match place_kernel's mapping (same grid/block shape).
__global__ __launch_bounds__(256) void rank_kernel(const int* __restrict__ dst,
                                                   int* __restrict__ degR,
                                                   int* __restrict__ rank, int E, int N) {
    int e = blockIdx.x * 256 + threadIdx.x;
    if (e < E) {
        int r = blockIdx.x & (R - 1);
        rank[e] = atomicAdd(&degR[(size_t)r * N + dst[e]], 1);
    }
}

// ---------------- fold replicas: offR (excl. scan over r), deg total, dinv ----
__global__ __launch_bounds__(256) void offR_kernel(const int* __restrict__ degR,
                                                   int* __restrict__ offR,
                                                   int* __restrict__ deg,
                                                   float* __restrict__ dinv, int N) {
    int i = blockIdx.x * 256 + threadIdx.x;
    if (i >= N) return;
    int run = 0;
#pragma unroll
    for (int r = 0; r < R; ++r) {
        int t = degR[(size_t)r * N + i];
        offR[(size_t)r * N + i] = run;
        run += t;
    }
    deg[i] = run;
    dinv[i] = rsqrtf((float)run + 1.0f);
}

// ---------------- scan step 1: per-block partial sums of deg ----------------
__global__ __launch_bounds__(SCAN_B) void scan_reduce(const int* __restrict__ deg,
                                                      int* __restrict__ partials, int N) {
    __shared__ int sh[SCAN_B];
    int t = threadIdx.x;
    int i = blockIdx.x * SCAN_B + t;
    sh[t] = (i < N) ? deg[i] : 0;
    __syncthreads();
    for (int off = SCAN_B / 2; off > 0; off >>= 1) {
        if (t < off) sh[t] += sh[t + off];
        __syncthreads();
    }
    if (t == 0) partials[blockIdx.x] = sh[0];
}

// ---------------- scan step 2: serial exclusive scan of partials; baseS[N]=E ----
__global__ void scan_partials(int* __restrict__ partials, int nb,
                              int* __restrict__ baseS, int N) {
    if (threadIdx.x == 0 && blockIdx.x == 0) {
        int run = 0;
        for (int i = 0; i < nb; ++i) {
            int t = partials[i];
            partials[i] = run;
            run += t;
        }
        baseS[N] = run;  // == E
    }
}

// ---------------- scan step 3: block-level exclusive scan + offset ----------------
__global__ __launch_bounds__(SCAN_B) void scan_apply(const int* __restrict__ deg,
                                                     const int* __restrict__ partials,
                                                     int* __restrict__ baseS, int N) {
    __shared__ int sh[SCAN_B];
    int t = threadIdx.x;
    int i = blockIdx.x * SCAN_B + t;
    int v = (i < N) ? deg[i] : 0;
    sh[t] = v;
    __syncthreads();
    for (int off = 1; off < SCAN_B; off <<= 1) {
        int add = (t >= off) ? sh[t - off] : 0;
        __syncthreads();
        sh[t] += add;
        __syncthreads();
    }
    if (i < N) baseS[i] = partials[blockIdx.x] + sh[t] - v;  // exclusive
}

// ---------------- placement: atomic-free counting sort by dst ----------------
__global__ __launch_bounds__(256) void place_kernel(const int* __restrict__ src,
                                                    const int* __restrict__ dst,
                                                    const int* __restrict__ rank,
                                                    const int* __restrict__ baseS,
                                                    const int* __restrict__ offR,
                                                    int* __restrict__ srcs, int E, int N) {
    int e = blockIdx.x * 256 + threadIdx.x;
    if (e < E) {
        int r = blockIdx.x & (R - 1);
        int d = dst[e];
        srcs[baseS[d] + offR[(size_t)r * N + d] + rank[e]] = src[e];
    }
}

// ---------------- pre-scaled fp16 x: xs[s] = fp16(x[s] * dinv[s]) ------
__global__ __launch_bounds__(256) void xs_kernel(const float* __restrict__ x,
                                                 const float* __restrict__ dinv,
                                                 __half* __restrict__ xs, int N) {
    int node = blockIdx.x * 4 + (threadIdx.x >> 6);
    if (node >= N) return;
    int lane = threadIdx.x & 63;
    float dv = dinv[node];
    size_t noff = (size_t)node * D;
    float2 v = ((const float2*)(x + noff))[lane];
    ((__half2*)(xs + noff))[lane] = __floats2half2_rn(v.x * dv, v.y * dv);
}

// ---------------- gather: one wave per node, fp16 packed rows ----------------
// agg[d] = dinv[d] * sum_e xs[src_e] + x[d]*dinv[d]^2 ; lane l -> cols 2l,2l+1
__global__ __launch_bounds__(256) void gather_kernel(const float* __restrict__ x,
                                                     const __half* __restrict__ xs,
                                                     const int* __restrict__ srcs,
                                                     const int* __restrict__ baseS,
                                                     const float* __restrict__ dinv,
                                                     float* __restrict__ agg, int N) {
    int node = blockIdx.x * 4 + (threadIdx.x >> 6);
    if (node >= N) return;
    int lane = threadIdx.x & 63;
    int start = baseS[node];
    int end = baseS[node + 1];
    float dvd = dinv[node];
    size_t noff = (size_t)node * D;
    const __half2* xs2 = (const __half2*)xs;  // row s at s*64 + lane

    float2 xv = ((const float2*)(x + noff))[lane];
    float s0 = 0.f, s1 = 0.f;

    int e = start;
    for (; e + 7 < end; e += 8) {
        int i0 = srcs[e + 0], i1 = srcs[e + 1], i2 = srcs[e + 2], i3 = srcs[e + 3];
        int i4 = srcs[e + 4], i5 = srcs[e + 5], i6 = srcs[e + 6], i7 = srcs[e + 7];
        float2 f0 = __half22float2(xs2[(size_t)i0 * 64 + lane]);
        float2 f1 = __half22float2(xs2[(size_t)i1 * 64 + lane]);
        float2 f2 = __half22float2(xs2[(size_t)i2 * 64 + lane]);
        float2 f3 = __half22float2(xs2[(size_t)i3 * 64 + lane]);
        float2 f4 = __half22float2(xs2[(size_t)i4 * 64 + lane]);
        float2 f5 = __half22float2(xs2[(size_t)i5 * 64 + lane]);
        float2 f6 = __half22float2(xs2[(size_t)i6 * 64 + lane]);
        float2 f7 = __half22float2(xs2[(size_t)i7 * 64 + lane]);
        s0 += (f0.x + f1.x) + (f2.x + f3.x) + ((f4.x + f5.x) + (f6.x + f7.x));
        s1 += (f0.y + f1.y) + (f2.y + f3.y) + ((f4.y + f5.y) + (f6.y + f7.y));
    }
    for (; e < end; ++e) {
        float2 f = __half22float2(xs2[(size_t)srcs[e] * 64 + lane]);
        s0 += f.x;
        s1 += f.y;
    }

    float acc0 = xv.x * dvd * dvd + s0 * dvd;
    float acc1 = xv.y * dvd * dvd + s1 * dvd;
    ((float2*)(agg + noff))[lane] = make_float2(acc0, acc1);
}

// ---------------- fused: out = x + relu(agg @ W^T + b) ----------
__global__ __launch_bounds__(256) void final_kernel(const float* __restrict__ agg,
                                                    const float* __restrict__ x,
                                                    const float* __restrict__ W,
                                                    const float* __restrict__ bias,
                                                    float* __restrict__ out, int N) {
    __shared__ float Wl[128 * 132];     // 67.6 KB
    __shared__ float rowbuf[16 * 128];  // 8 KB
    const int lane = threadIdx.x & 63;
    const int wave = threadIdx.x >> 6;

    for (int idx = threadIdx.x; idx < 128 * 32; idx += 256) {
        int j = idx >> 5, c = idx & 31;
        float4 w = ((const float4*)W)[idx];
        *(float4*)&Wl[j * 132 + c * 4] = w;
    }

    int base = blockIdx.x * 16;
    int trow = threadIdx.x >> 4;
    int tc = threadIdx.x & 15;
    int grow = base + trow;
    if (grow < N) {
        size_t off = (size_t)grow * D;
        const float4* a4 = (const float4*)(agg + off);
        *(float4*)&rowbuf[trow * D + tc * 4] = a4[tc];
        *(float4*)&rowbuf[trow * D + (tc + 16) * 4] = a4[tc + 16];
    }
    __syncthreads();

    const int j0 = lane, j1 = lane + 64;
    float acc0[4] = {0.f, 0.f, 0.f, 0.f};
    float acc1[4] = {0.f, 0.f, 0.f, 0.f};
    const float* w0p = &Wl[j0 * 132];
    const float* w1p = &Wl[j1 * 132];
    const float* rp = &rowbuf[wave * 4 * D];
#pragma unroll 4
    for (int c = 0; c < 32; ++c) {
        float4 w0 = *(const float4*)(w0p + c * 4);
        float4 w1 = *(const float4*)(w1p + c * 4);
#pragma unroll
        for (int r = 0; r < 4; ++r) {
            float4 rv = *(const float4*)(rp + r * D + c * 4);
            acc0[r] += rv.x * w0.x + rv.y * w0.y + rv.z * w0.z + rv.w * w0.w;
            acc1[r] += rv.x * w1.x + rv.y * w1.y + rv.z * w1.z + rv.w * w1.w;
        }
    }

    float b0 = bias[j0], b1 = bias[j1];
#pragma unroll
    for (int r = 0; r < 4; ++r) {
        int row = base + wave * 4 + r;
        if (row < N) {
            size_t off = (size_t)row * D;
            float h0 = acc0[r] + b0;
            float h1 = acc1[r] + b1;
            out[off + j0] = x[off + j0] + (h0 > 0.f ? h0 : 0.f);
            out[off + j1] = x[off + j1] + (h1 > 0.f ? h1 : 0.f);
        }
    }
}

extern "C" void kernel_launch(void* const* d_in, const int* in_sizes, int n_in,
                              void* d_out, int out_size, void* d_ws, size_t ws_size,
                              hipStream_t stream) {
    const float* x = (const float*)d_in[0];
    const int* ei = (const int*)d_in[1];
    const float* W = (const float*)d_in[2];
    const float* bias = (const float*)d_in[3];
    float* out = (float*)d_out;

    const int N = in_sizes[0] / D;   // 50000
    const int E = in_sizes[1] / 2;   // 1,600,000
    const int* src = ei;
    const int* dst = ei + E;

    const int nb = (N + SCAN_B - 1) / SCAN_B;

    // workspace layout. The tail region [degR|offR|rank] (1.6+1.6+6.4 MB) is
    // dead after place_kernel; xs (fp16, 12.8 MB) overlays it — xs_kernel runs
    // after place_kernel and before gather_kernel.
    char* p = (char*)d_ws;
    float* agg = (float*)p;   p += (size_t)N * D * sizeof(float);    // 25.6 MB
    int* deg = (int*)p;       p += (size_t)N * sizeof(int);          // totals
    int* baseS = (int*)p;     p += (size_t)(N + 1) * sizeof(int);
    float* dinv = (float*)p;  p += (size_t)N * sizeof(float);
    int* partials = (int*)p;  p += (size_t)nb * sizeof(int);
    int* srcs = (int*)p;      p += (size_t)E * sizeof(int);          // 6.4 MB
    char* tail = p;
    int* degR = (int*)tail;                                          // R*N ints
    int* offR = (int*)(tail + (size_t)R * N * sizeof(int));          // R*N ints
    int* rank = (int*)(tail + (size_t)2 * R * N * sizeof(int));      // E ints
    __half* xs = (__half*)tail;                                      // overlays

    hipMemsetAsync(degR, 0, (size_t)R * N * sizeof(int), stream);

    rank_kernel<<<(E + 255) / 256, 256, 0, stream>>>(dst, degR, rank, E, N);

    offR_kernel<<<(N + 255) / 256, 256, 0, stream>>>(degR, offR, deg, dinv, N);

    scan_reduce<<<nb, SCAN_B, 0, stream>>>(deg, partials, N);
    scan_partials<<<1, 64, 0, stream>>>(partials, nb, baseS, N);
    scan_apply<<<nb, SCAN_B, 0, stream>>>(deg, partials, baseS, N);

    place_kernel<<<(E + 255) / 256, 256, 0, stream>>>(src, dst, rank, baseS, offR, srcs, E, N);

    xs_kernel<<<(N + 3) / 4, 256, 0, stream>>>(x, dinv, xs, N);

    gather_kernel<<<(N + 3) / 4, 256, 0, stream>>>(x, xs, srcs, baseS, dinv, agg, N);

    final_kernel<<<(N + 15) / 16, 256, 0, stream>>>(agg, x, W, bias, out, N);
}

// Round 6
// 277.403 us; speedup vs baseline: 1.2119x; 1.2119x over previous
//
#include <hip/hip_runtime.h>
#include <hip/hip_fp16.h>

#define D 128
#define SCAN_B 256
#define R 8  // degree-counter replicas (contention spreading)

using half8 = __attribute__((ext_vector_type(8))) _Float16;
using float4v = __attribute__((ext_vector_type(4))) float;

// ---------------- replicated degree + rank: rank[e] = degR[r][dst[e]]++ -------
// r = blockIdx & 7 — MUST match place_kernel's mapping (same grid/block shape).
__global__ __launch_bounds__(256) void rank_kernel(const int* __restrict__ dst,
                                                   int* __restrict__ degR,
                                                   int* __restrict__ rank, int E, int N) {
    int e = blockIdx.x * 256 + threadIdx.x;
    if (e < E) {
        int r = blockIdx.x & (R - 1);
        rank[e] = atomicAdd(&degR[(size_t)r * N + dst[e]], 1);
    }
}

// ---------------- fold replicas: offR (excl. scan over r), deg total, dinv ----
__global__ __launch_bounds__(256) void offR_kernel(const int* __restrict__ degR,
                                                   int* __restrict__ offR,
                                                   int* __restrict__ deg,
                                                   float* __restrict__ dinv, int N) {
    int i = blockIdx.x * 256 + threadIdx.x;
    if (i >= N) return;
    int run = 0;
#pragma unroll
    for (int r = 0; r < R; ++r) {
        int t = degR[(size_t)r * N + i];
        offR[(size_t)r * N + i] = run;
        run += t;
    }
    deg[i] = run;
    dinv[i] = rsqrtf((float)run + 1.0f);
}

// ---------------- scan step 1: per-block partial sums of deg ----------------
__global__ __launch_bounds__(SCAN_B) void scan_reduce(const int* __restrict__ deg,
                                                      int* __restrict__ partials, int N) {
    __shared__ int sh[SCAN_B];
    int t = threadIdx.x;
    int i = blockIdx.x * SCAN_B + t;
    sh[t] = (i < N) ? deg[i] : 0;
    __syncthreads();
    for (int off = SCAN_B / 2; off > 0; off >>= 1) {
        if (t < off) sh[t] += sh[t + off];
        __syncthreads();
    }
    if (t == 0) partials[blockIdx.x] = sh[0];
}

// ---------------- scan step 2: serial exclusive scan of partials; baseS[N]=E ----
__global__ void scan_partials(int* __restrict__ partials, int nb,
                              int* __restrict__ baseS, int N) {
    if (threadIdx.x == 0 && blockIdx.x == 0) {
        int run = 0;
        for (int i = 0; i < nb; ++i) {
            int t = partials[i];
            partials[i] = run;
            run += t;
        }
        baseS[N] = run;  // == E
    }
}

// ---------------- scan step 3: block-level exclusive scan + offset ----------------
__global__ __launch_bounds__(SCAN_B) void scan_apply(const int* __restrict__ deg,
                                                     const int* __restrict__ partials,
                                                     int* __restrict__ baseS, int N) {
    __shared__ int sh[SCAN_B];
    int t = threadIdx.x;
    int i = blockIdx.x * SCAN_B + t;
    int v = (i < N) ? deg[i] : 0;
    sh[t] = v;
    __syncthreads();
    for (int off = 1; off < SCAN_B; off <<= 1) {
        int add = (t >= off) ? sh[t - off] : 0;
        __syncthreads();
        sh[t] += add;
        __syncthreads();
    }
    if (i < N) baseS[i] = partials[blockIdx.x] + sh[t] - v;  // exclusive
}

// ---------------- placement: atomic-free counting sort by dst ----------------
__global__ __launch_bounds__(256) void place_kernel(const int* __restrict__ src,
                                                    const int* __restrict__ dst,
                                                    const int* __restrict__ rank,
                                                    const int* __restrict__ baseS,
                                                    const int* __restrict__ offR,
                                                    int* __restrict__ srcs, int E, int N) {
    int e = blockIdx.x * 256 + threadIdx.x;
    if (e < E) {
        int r = blockIdx.x & (R - 1);
        int d = dst[e];
        srcs[baseS[d] + offR[(size_t)r * N + d] + rank[e]] = src[e];
    }
}

// ---------------- xw = (x * dinv) @ W^T via MFMA f16, sigma-permuted cols -----
// xw[row] stored as 128 fp16 at half-index sigma(col) = (col%16)*8 + col/16.
// Block: 256 thr (4 waves), 64 rows. W staged in LDS in B-fragment layout.
// MFMA 16x16x32_f16: A[m=lane&15][k=(lane>>4)*8+j]; B[k=(lane>>4)*8+j][n=lane&15];
// D: col=lane&15, row=(lane>>4)*4+reg.  (layouts per m89/m91/m120)
__global__ __launch_bounds__(256) void xw_kernel(const float* __restrict__ x,
                                                 const float* __restrict__ dinv,
                                                 const float* __restrict__ W,
                                                 __half* __restrict__ xw, int N) {
    __shared__ _Float16 Bf[128 * 128];  // 32 KB, fragment-ordered
    const int t = threadIdx.x;

    // stage B[k][n] = W[n][k] into fragment layout:
    // halfidx = (((kt*8+jt)*4+quad)*16 + nlo)*8 + u ;  k=kt*32+quad*8+u, n=jt*16+nlo
    {
        int n = t >> 1;
        int jt = n >> 4, nlo = n & 15;
        int kbase = (t & 1) * 64;
#pragma unroll
        for (int o = 0; o < 8; ++o) {
            int k0 = kbase + o * 8;
            float4 f0 = *(const float4*)&W[n * 128 + k0];
            float4 f1 = *(const float4*)&W[n * 128 + k0 + 4];
            int kt = k0 >> 5, quad = (k0 >> 3) & 3;
            half8 h;
            h[0] = (_Float16)f0.x; h[1] = (_Float16)f0.y;
            h[2] = (_Float16)f0.z; h[3] = (_Float16)f0.w;
            h[4] = (_Float16)f1.x; h[5] = (_Float16)f1.y;
            h[6] = (_Float16)f1.z; h[7] = (_Float16)f1.w;
            *(half8*)&Bf[(size_t)(((kt * 8 + jt) * 4 + quad) * 16 + nlo) * 8] = h;
        }
    }
    __syncthreads();

    const int wave = t >> 6, lane = t & 63;
    const int quad = lane >> 4, nlo = lane & 15;
    const int r0 = blockIdx.x * 64 + wave * 16;
    const int rA = r0 + nlo;                 // A row for this lane (m = lane&15)
    const int rAc = (rA < N) ? rA : (N - 1); // clamp (stores guarded)
    const float dv = dinv[rAc];

    float4v acc[8];
#pragma unroll
    for (int j = 0; j < 8; ++j) acc[j] = (float4v){0.f, 0.f, 0.f, 0.f};

#pragma unroll
    for (int kt = 0; kt < 4; ++kt) {
        const float* xp = x + (size_t)rAc * D + kt * 32 + quad * 8;
        float4 a0 = *(const float4*)xp;
        float4 a1 = *(const float4*)(xp + 4);
        half8 va;
        va[0] = (_Float16)(a0.x * dv); va[1] = (_Float16)(a0.y * dv);
        va[2] = (_Float16)(a0.z * dv); va[3] = (_Float16)(a0.w * dv);
        va[4] = (_Float16)(a1.x * dv); va[5] = (_Float16)(a1.y * dv);
        va[6] = (_Float16)(a1.z * dv); va[7] = (_Float16)(a1.w * dv);
#pragma unroll
        for (int jt = 0; jt < 8; ++jt) {
            half8 vb = *(half8*)&Bf[(size_t)((kt * 8 + jt) * 64 + lane) * 8];
            acc[jt] = __builtin_amdgcn_mfma_f32_16x16x32_f16(va, vb, acc[jt], 0, 0, 0);
        }
    }

    // store: row = r0 + quad*4 + reg; lane's 8 jt-values -> sigma halves nlo*8+jt
#pragma unroll
    for (int reg = 0; reg < 4; ++reg) {
        int row = r0 + quad * 4 + reg;
        if (row < N) {
            half8 h;
#pragma unroll
            for (int jt = 0; jt < 8; ++jt) h[jt] = (_Float16)acc[jt][reg];
            *(half8*)((_Float16*)xw + (size_t)row * D + nlo * 8) = h;
        }
    }
}

// ---------------- gather + fused epilogue ----------------
// out[d][c] = x[d][c] + relu(dinv[d]*(xw[d] + sum_e xw[src_e]) + b[c])
// xw rows are sigma-permuted: lane l's half2 (halves 2l,2l+1) = real cols
// c0=(l&3)*32+(l>>2), c1=c0+16.
__global__ __launch_bounds__(256) void gather_kernel(const float* __restrict__ x,
                                                     const __half* __restrict__ xw,
                                                     const int* __restrict__ srcs,
                                                     const int* __restrict__ baseS,
                                                     const float* __restrict__ dinv,
                                                     const float* __restrict__ bias,
                                                     float* __restrict__ out, int N) {
    int node = blockIdx.x * 4 + (threadIdx.x >> 6);
    if (node >= N) return;
    int lane = threadIdx.x & 63;
    int start = baseS[node];
    int end = baseS[node + 1];
    float dvd = dinv[node];
    size_t noff = (size_t)node * D;
    const __half2* xw2 = (const __half2*)xw;  // row s at s*64 + lane

    // self term: xw[node]
    float2 fs = __half22float2(xw2[(size_t)node * 64 + lane]);
    float s0 = fs.x, s1 = fs.y;

    int e = start;
    for (; e + 7 < end; e += 8) {
        int i0 = srcs[e + 0], i1 = srcs[e + 1], i2 = srcs[e + 2], i3 = srcs[e + 3];
        int i4 = srcs[e + 4], i5 = srcs[e + 5], i6 = srcs[e + 6], i7 = srcs[e + 7];
        float2 f0 = __half22float2(xw2[(size_t)i0 * 64 + lane]);
        float2 f1 = __half22float2(xw2[(size_t)i1 * 64 + lane]);
        float2 f2 = __half22float2(xw2[(size_t)i2 * 64 + lane]);
        float2 f3 = __half22float2(xw2[(size_t)i3 * 64 + lane]);
        float2 f4 = __half22float2(xw2[(size_t)i4 * 64 + lane]);
        float2 f5 = __half22float2(xw2[(size_t)i5 * 64 + lane]);
        float2 f6 = __half22float2(xw2[(size_t)i6 * 64 + lane]);
        float2 f7 = __half22float2(xw2[(size_t)i7 * 64 + lane]);
        s0 += (f0.x + f1.x) + (f2.x + f3.x) + ((f4.x + f5.x) + (f6.x + f7.x));
        s1 += (f0.y + f1.y) + (f2.y + f3.y) + ((f4.y + f5.y) + (f6.y + f7.y));
    }
    for (; e < end; ++e) {
        float2 f = __half22float2(xw2[(size_t)srcs[e] * 64 + lane]);
        s0 += f.x;
        s1 += f.y;
    }

    int c0 = (lane & 3) * 32 + (lane >> 2);
    int c1 = c0 + 16;
    float h0 = s0 * dvd + bias[c0];
    float h1 = s1 * dvd + bias[c1];
    out[noff + c0] = x[noff + c0] + (h0 > 0.f ? h0 : 0.f);
    out[noff + c1] = x[noff + c1] + (h1 > 0.f ? h1 : 0.f);
}

extern "C" void kernel_launch(void* const* d_in, const int* in_sizes, int n_in,
                              void* d_out, int out_size, void* d_ws, size_t ws_size,
                              hipStream_t stream) {
    const float* x = (const float*)d_in[0];
    const int* ei = (const int*)d_in[1];
    const float* W = (const float*)d_in[2];
    const float* bias = (const float*)d_in[3];
    float* out = (float*)d_out;

    const int N = in_sizes[0] / D;   // 50000
    const int E = in_sizes[1] / 2;   // 1,600,000
    const int* src = ei;
    const int* dst = ei + E;

    const int nb = (N + SCAN_B - 1) / SCAN_B;

    // workspace layout (~29 MB)
    char* p = (char*)d_ws;
    __half* xw = (__half*)p; p += (size_t)N * D * sizeof(__half);    // 12.8 MB
    int* deg = (int*)p;      p += (size_t)N * sizeof(int);
    int* baseS = (int*)p;    p += (size_t)(N + 1) * sizeof(int);
    float* dinv = (float*)p; p += (size_t)N * sizeof(float);
    int* partials = (int*)p; p += (size_t)nb * sizeof(int);
    int* srcs = (int*)p;     p += (size_t)E * sizeof(int);           // 6.4 MB
    int* degR = (int*)p;     p += (size_t)R * N * sizeof(int);       // 1.6 MB
    int* offR = (int*)p;     p += (size_t)R * N * sizeof(int);       // 1.6 MB
    int* rank = (int*)p;     p += (size_t)E * sizeof(int);           // 6.4 MB

    hipMemsetAsync(degR, 0, (size_t)R * N * sizeof(int), stream);

    rank_kernel<<<(E + 255) / 256, 256, 0, stream>>>(dst, degR, rank, E, N);

    offR_kernel<<<(N + 255) / 256, 256, 0, stream>>>(degR, offR, deg, dinv, N);

    // xw GEMM (needs dinv only)
    xw_kernel<<<(N + 63) / 64, 256, 0, stream>>>(x, dinv, W, xw, N);

    scan_reduce<<<nb, SCAN_B, 0, stream>>>(deg, partials, N);
    scan_partials<<<1, 64, 0, stream>>>(partials, nb, baseS, N);
    scan_apply<<<nb, SCAN_B, 0, stream>>>(deg, partials, baseS, N);

    place_kernel<<<(E + 255) / 256, 256, 0, stream>>>(src, dst, rank, baseS, offR, srcs, E, N);

    gather_kernel<<<(N + 3) / 4, 256, 0, stream>>>(x, xw, srcs, baseS, dinv, bias, out, N);
}

// Round 7
// 276.365 us; speedup vs baseline: 1.2164x; 1.0038x over previous
//
#include <hip/hip_runtime.h>
#include <hip/hip_fp16.h>

#define D 128
#define CAP 128          // per-node slot capacity (Poisson(32) max deg ~70 << 128)
#define OVF_CAP 131072   // spill capacity (pairs); statistically never used

using half8 = __attribute__((ext_vector_type(8))) _Float16;
using float4v = __attribute__((ext_vector_type(4))) float;

// ---------------- fused count + place: one pass, no scans, no second pass ----
// p = deg[dst]++ ; srcs_padded[dst*CAP + p] = src.  Overflow -> spill list.
__global__ __launch_bounds__(256) void rank_place_kernel(const int* __restrict__ src,
                                                         const int* __restrict__ dst,
                                                         int* __restrict__ deg,
                                                         int* __restrict__ srcs,
                                                         int* __restrict__ ovf_cnt,
                                                         int2* __restrict__ ovf, int E) {
    int e = blockIdx.x * 256 + threadIdx.x;
    if (e < E) {
        int d = dst[e];
        int s = src[e];
        int p = atomicAdd(&deg[d], 1);
        if (p < CAP) {
            srcs[(size_t)d * CAP + p] = s;
        } else {
            int q = atomicAdd(ovf_cnt, 1);
            if (q < OVF_CAP) ovf[q] = make_int2(d, s);
        }
    }
}

// ---------------- dinv = rsqrt(deg + 1 self-loop) ----------------
__global__ __launch_bounds__(256) void dinv_kernel(const int* __restrict__ deg,
                                                   float* __restrict__ dinv, int N) {
    int i = blockIdx.x * 256 + threadIdx.x;
    if (i < N) dinv[i] = rsqrtf((float)deg[i] + 1.0f);
}

// ---------------- xw = (x * dinv) @ W^T via MFMA f16, sigma-permuted cols -----
// xw[row] stored as 128 fp16 at half-index sigma(col) = (col%16)*8 + col/16.
// Block: 256 thr (4 waves), 64 rows. W staged in LDS in B-fragment layout.
// MFMA 16x16x32_f16: A[m=lane&15][k=(lane>>4)*8+j]; B[k=(lane>>4)*8+j][n=lane&15];
// D: col=lane&15, row=(lane>>4)*4+reg.  (layouts per m89/m91/m120)
__global__ __launch_bounds__(256) void xw_kernel(const float* __restrict__ x,
                                                 const float* __restrict__ dinv,
                                                 const float* __restrict__ W,
                                                 __half* __restrict__ xw, int N) {
    __shared__ _Float16 Bf[128 * 128];  // 32 KB, fragment-ordered
    const int t = threadIdx.x;

    // stage B[k][n] = W[n][k] into fragment layout:
    // halfidx = (((kt*8+jt)*4+quad)*16 + nlo)*8 + u ;  k=kt*32+quad*8+u, n=jt*16+nlo
    {
        int n = t >> 1;
        int jt = n >> 4, nlo = n & 15;
        int kbase = (t & 1) * 64;
#pragma unroll
        for (int o = 0; o < 8; ++o) {
            int k0 = kbase + o * 8;
            float4 f0 = *(const float4*)&W[n * 128 + k0];
            float4 f1 = *(const float4*)&W[n * 128 + k0 + 4];
            int kt = k0 >> 5, quad = (k0 >> 3) & 3;
            half8 h;
            h[0] = (_Float16)f0.x; h[1] = (_Float16)f0.y;
            h[2] = (_Float16)f0.z; h[3] = (_Float16)f0.w;
            h[4] = (_Float16)f1.x; h[5] = (_Float16)f1.y;
            h[6] = (_Float16)f1.z; h[7] = (_Float16)f1.w;
            *(half8*)&Bf[(size_t)(((kt * 8 + jt) * 4 + quad) * 16 + nlo) * 8] = h;
        }
    }
    __syncthreads();

    const int wave = t >> 6, lane = t & 63;
    const int quad = lane >> 4, nlo = lane & 15;
    const int r0 = blockIdx.x * 64 + wave * 16;
    const int rA = r0 + nlo;                 // A row for this lane (m = lane&15)
    const int rAc = (rA < N) ? rA : (N - 1); // clamp (stores guarded)
    const float dv = dinv[rAc];

    float4v acc[8];
#pragma unroll
    for (int j = 0; j < 8; ++j) acc[j] = (float4v){0.f, 0.f, 0.f, 0.f};

#pragma unroll
    for (int kt = 0; kt < 4; ++kt) {
        const float* xp = x + (size_t)rAc * D + kt * 32 + quad * 8;
        float4 a0 = *(const float4*)xp;
        float4 a1 = *(const float4*)(xp + 4);
        half8 va;
        va[0] = (_Float16)(a0.x * dv); va[1] = (_Float16)(a0.y * dv);
        va[2] = (_Float16)(a0.z * dv); va[3] = (_Float16)(a0.w * dv);
        va[4] = (_Float16)(a1.x * dv); va[5] = (_Float16)(a1.y * dv);
        va[6] = (_Float16)(a1.z * dv); va[7] = (_Float16)(a1.w * dv);
#pragma unroll
        for (int jt = 0; jt < 8; ++jt) {
            half8 vb = *(half8*)&Bf[(size_t)((kt * 8 + jt) * 64 + lane) * 8];
            acc[jt] = __builtin_amdgcn_mfma_f32_16x16x32_f16(va, vb, acc[jt], 0, 0, 0);
        }
    }

    // store: row = r0 + quad*4 + reg; lane's 8 jt-values -> sigma halves nlo*8+jt
#pragma unroll
    for (int reg = 0; reg < 4; ++reg) {
        int row = r0 + quad * 4 + reg;
        if (row < N) {
            half8 h;
#pragma unroll
            for (int jt = 0; jt < 8; ++jt) h[jt] = (_Float16)acc[jt][reg];
            *(half8*)((_Float16*)xw + (size_t)row * D + nlo * 8) = h;
        }
    }
}

// ---------------- gather + fused epilogue ----------------
// out[d][c] = x[d][c] + relu(dinv[d]*(xw[d] + sum_e xw[src_e]) + b[c])
// xw rows are sigma-permuted: lane l's half2 (halves 2l,2l+1) = real cols
// c0=(l&3)*32+(l>>2), c1=c0+16.
__global__ __launch_bounds__(256) void gather_kernel(const float* __restrict__ x,
                                                     const __half* __restrict__ xw,
                                                     const int* __restrict__ srcs,
                                                     const int* __restrict__ deg,
                                                     const float* __restrict__ dinv,
                                                     const float* __restrict__ bias,
                                                     const int* __restrict__ ovf_cnt,
                                                     const int2* __restrict__ ovf,
                                                     float* __restrict__ out, int N) {
    int node = blockIdx.x * 4 + (threadIdx.x >> 6);
    if (node >= N) return;
    int lane = threadIdx.x & 63;
    int degn = deg[node];
    int end = (degn < CAP) ? degn : CAP;
    float dvd = dinv[node];
    size_t noff = (size_t)node * D;
    const __half2* xw2 = (const __half2*)xw;  // row s at s*64 + lane
    const int* sp = srcs + (size_t)node * CAP;

    // self term: xw[node]
    float2 fs = __half22float2(xw2[(size_t)node * 64 + lane]);
    float s0 = fs.x, s1 = fs.y;

    int e = 0;
    for (; e + 7 < end; e += 8) {
        int i0 = sp[e + 0], i1 = sp[e + 1], i2 = sp[e + 2], i3 = sp[e + 3];
        int i4 = sp[e + 4], i5 = sp[e + 5], i6 = sp[e + 6], i7 = sp[e + 7];
        float2 f0 = __half22float2(xw2[(size_t)i0 * 64 + lane]);
        float2 f1 = __half22float2(xw2[(size_t)i1 * 64 + lane]);
        float2 f2 = __half22float2(xw2[(size_t)i2 * 64 + lane]);
        float2 f3 = __half22float2(xw2[(size_t)i3 * 64 + lane]);
        float2 f4 = __half22float2(xw2[(size_t)i4 * 64 + lane]);
        float2 f5 = __half22float2(xw2[(size_t)i5 * 64 + lane]);
        float2 f6 = __half22float2(xw2[(size_t)i6 * 64 + lane]);
        float2 f7 = __half22float2(xw2[(size_t)i7 * 64 + lane]);
        s0 += (f0.x + f1.x) + (f2.x + f3.x) + ((f4.x + f5.x) + (f6.x + f7.x));
        s1 += (f0.y + f1.y) + (f2.y + f3.y) + ((f4.y + f5.y) + (f6.y + f7.y));
    }
    for (; e < end; ++e) {
        float2 f = __half22float2(xw2[(size_t)sp[e] * 64 + lane]);
        s0 += f.x;
        s1 += f.y;
    }

    // overflow spill (statistically empty; one uniform load when empty)
    int novf = *ovf_cnt;
    if (novf > 0) {
        if (novf > OVF_CAP) novf = OVF_CAP;
        for (int k = 0; k < novf; ++k) {
            int2 pr = ovf[k];
            if (pr.x == node) {
                float2 f = __half22float2(xw2[(size_t)pr.y * 64 + lane]);
                s0 += f.x;
                s1 += f.y;
            }
        }
    }

    int c0 = (lane & 3) * 32 + (lane >> 2);
    int c1 = c0 + 16;
    float h0 = s0 * dvd + bias[c0];
    float h1 = s1 * dvd + bias[c1];
    out[noff + c0] = x[noff + c0] + (h0 > 0.f ? h0 : 0.f);
    out[noff + c1] = x[noff + c1] + (h1 > 0.f ? h1 : 0.f);
}

extern "C" void kernel_launch(void* const* d_in, const int* in_sizes, int n_in,
                              void* d_out, int out_size, void* d_ws, size_t ws_size,
                              hipStream_t stream) {
    const float* x = (const float*)d_in[0];
    const int* ei = (const int*)d_in[1];
    const float* W = (const float*)d_in[2];
    const float* bias = (const float*)d_in[3];
    float* out = (float*)d_out;

    const int N = in_sizes[0] / D;   // 50000
    const int E = in_sizes[1] / 2;   // 1,600,000
    const int* src = ei;
    const int* dst = ei + E;

    // workspace layout (~41 MB): xw | deg | dinv | ovf_cnt | ovf | srcs_padded
    char* p = (char*)d_ws;
    __half* xw = (__half*)p;  p += (size_t)N * D * sizeof(__half);     // 12.8 MB
    int* deg = (int*)p;       p += (size_t)N * sizeof(int);            // 0.2 MB
    float* dinv = (float*)p;  p += (size_t)N * sizeof(float);          // 0.2 MB
    int* ovf_cnt = (int*)p;   p += 16;                                 // counter
    int2* ovf = (int2*)p;     p += (size_t)OVF_CAP * sizeof(int2);     // 1 MB
    int* srcs = (int*)p;      p += (size_t)N * CAP * sizeof(int);      // 25.6 MB

    // zero deg + ovf_cnt (deg..ovf_cnt are contiguous through dinv; just zero
    // the two small ranges in one memset spanning deg..ovf_cnt inclusive)
    hipMemsetAsync(deg, 0, (size_t)N * (sizeof(int) + sizeof(float)) + 16, stream);

    rank_place_kernel<<<(E + 255) / 256, 256, 0, stream>>>(src, dst, deg, srcs,
                                                           ovf_cnt, ovf, E);

    dinv_kernel<<<(N + 255) / 256, 256, 0, stream>>>(deg, dinv, N);

    xw_kernel<<<(N + 63) / 64, 256, 0, stream>>>(x, dinv, W, xw, N);

    gather_kernel<<<(N + 3) / 4, 256, 0, stream>>>(x, xw, srcs, deg, dinv, bias,
                                                   ovf_cnt, ovf, out, N);
}

// Round 8
// 204.558 us; speedup vs baseline: 1.6434x; 1.3510x over previous
//
#include <hip/hip_runtime.h>
#include <hip/hip_fp16.h>

#define D 128
#define CAP 128          // per-node slot capacity (deg ~ Poisson(32), max ~72)
#define BSHIFT 6
#define BSIZE 64         // nodes per bucket
#define NBMAX 1024       // supports N <= 65536
#define BCAP 3072        // slab capacity per bucket (E[cnt]=2046, >20 sigma safe)
#define PA_BLOCKS 256
#define OVF_CAP 65536

using half8 = __attribute__((ext_vector_type(8))) _Float16;
using float4v = __attribute__((ext_vector_type(4))) float;

// ---- A1: per-block LDS histogram of dst>>6; write block-major partials ------
__global__ __launch_bounds__(256) void histA_kernel(const int* __restrict__ dst,
                                                    int* __restrict__ ph, int E, int NB) {
    __shared__ int hist[NBMAX];
    int t = threadIdx.x;
    for (int b = t; b < NB; b += 256) hist[b] = 0;
    __syncthreads();
    int chunk = (E + gridDim.x - 1) / gridDim.x;
    int start = blockIdx.x * chunk;
    int end = min(start + chunk, E);
    for (int i = start + t; i < end; i += 256)
        atomicAdd(&hist[dst[i] >> BSHIFT], 1);
    __syncthreads();
    int* row = ph + (size_t)blockIdx.x * NB;
    for (int b = t; b < NB; b += 256) row[b] = hist[b];
}

// ---- A2: per-bucket exclusive scan over the 256 block partials --------------
__global__ __launch_bounds__(PA_BLOCKS) void scanA_kernel(int* __restrict__ ph,
                                                          int* __restrict__ bucket_cnt,
                                                          int NB) {
    __shared__ int sh[PA_BLOCKS];
    int b = blockIdx.x;
    int t = threadIdx.x;
    int v = ph[(size_t)t * NB + b];
    sh[t] = v;
    __syncthreads();
    for (int off = 1; off < PA_BLOCKS; off <<= 1) {
        int add = (t >= off) ? sh[t - off] : 0;
        __syncthreads();
        sh[t] += add;
        __syncthreads();
    }
    ph[(size_t)t * NB + b] = sh[t] - v;  // exclusive offset for (block t, bucket b)
    if (t == PA_BLOCKS - 1) bucket_cnt[b] = sh[t];
}

// ---- A3: replay edges; place (src, dst&63) into bucket slabs, LDS cursors ---
__global__ __launch_bounds__(256) void placeA_kernel(const int* __restrict__ src,
                                                     const int* __restrict__ dst,
                                                     const int* __restrict__ ph,
                                                     int2* __restrict__ pairs,
                                                     int* __restrict__ ovfA_cnt,
                                                     int2* __restrict__ ovfA,
                                                     int E, int NB) {
    __shared__ int sbase[NBMAX];
    __shared__ int cur[NBMAX];
    int t = threadIdx.x;
    const int* row = ph + (size_t)blockIdx.x * NB;
    for (int b = t; b < NB; b += 256) { sbase[b] = row[b]; cur[b] = 0; }
    __syncthreads();
    int chunk = (E + gridDim.x - 1) / gridDim.x;
    int start = blockIdx.x * chunk;
    int end = min(start + chunk, E);
    for (int i = start + t; i < end; i += 256) {
        int dd = dst[i];
        int b = dd >> BSHIFT;
        int p = sbase[b] + atomicAdd(&cur[b], 1);
        if (p < BCAP) {
            pairs[(size_t)b * BCAP + p] = make_int2(src[i], dd & (BSIZE - 1));
        } else {  // slab overflow (statistically never): spill, deg fixed later
            int q = atomicAdd(ovfA_cnt, 1);
            if (q < OVF_CAP) ovfA[q] = make_int2(dd, src[i]);
        }
    }
}

// ---- B: per-bucket scatter into padded per-node lists; exact deg ------------
__global__ __launch_bounds__(256) void bucketB_kernel(const int2* __restrict__ pairs,
                                                      const int* __restrict__ bucket_cnt,
                                                      int* __restrict__ srcs,
                                                      int* __restrict__ deg,
                                                      int* __restrict__ ovfB_cnt,
                                                      int2* __restrict__ ovfB,
                                                      int N, int NB) {
    __shared__ int deg64[BSIZE];
    int b = blockIdx.x;
    int t = threadIdx.x;
    if (t < BSIZE) deg64[t] = 0;
    __syncthreads();
    int cnt = bucket_cnt[b];
    if (cnt > BCAP) cnt = BCAP;
    const int2* pp = pairs + (size_t)b * BCAP;
    for (int i = t; i < cnt; i += 256) {
        int2 pr = pp[i];
        int dl = pr.y;
        int p = atomicAdd(&deg64[dl], 1);
        int node = b * BSIZE + dl;
        if (p < CAP) {
            srcs[(size_t)node * CAP + p] = pr.x;
        } else {  // node capacity overflow: spill (deg64 already counted it)
            int q = atomicAdd(ovfB_cnt, 1);
            if (q < OVF_CAP) ovfB[q] = make_int2(node, pr.x);
        }
    }
    __syncthreads();
    if (t < BSIZE) {
        int node = b * BSIZE + t;
        if (node < N) deg[node] = deg64[t];
    }
}

// ---- deg fixup for A-phase spills (empty in practice) -----------------------
__global__ void degfix_kernel(const int* __restrict__ ovfA_cnt,
                              const int2* __restrict__ ovfA, int* __restrict__ deg) {
    int n = *ovfA_cnt;
    if (n > OVF_CAP) n = OVF_CAP;
    for (int k = threadIdx.x; k < n; k += blockDim.x)
        atomicAdd(&deg[ovfA[k].x], 1);
}

// ---------------- dinv = rsqrt(deg + 1 self-loop) ----------------
__global__ __launch_bounds__(256) void dinv_kernel(const int* __restrict__ deg,
                                                   float* __restrict__ dinv, int N) {
    int i = blockIdx.x * 256 + threadIdx.x;
    if (i < N) dinv[i] = rsqrtf((float)deg[i] + 1.0f);
}

// ---------------- xw = (x * dinv) @ W^T via MFMA f16, sigma-permuted cols -----
// xw[row] stored as 128 fp16 at half-index sigma(col) = (col%16)*8 + col/16.
// MFMA 16x16x32_f16: A[m=lane&15][k=(lane>>4)*8+j]; B[k][n=lane&15];
// D: col=lane&15, row=(lane>>4)*4+reg.
__global__ __launch_bounds__(256) void xw_kernel(const float* __restrict__ x,
                                                 const float* __restrict__ dinv,
                                                 const float* __restrict__ W,
                                                 __half* __restrict__ xw, int N) {
    __shared__ _Float16 Bf[128 * 128];  // 32 KB, fragment-ordered
    const int t = threadIdx.x;
    {
        int n = t >> 1;
        int jt = n >> 4, nlo = n & 15;
        int kbase = (t & 1) * 64;
#pragma unroll
        for (int o = 0; o < 8; ++o) {
            int k0 = kbase + o * 8;
            float4 f0 = *(const float4*)&W[n * 128 + k0];
            float4 f1 = *(const float4*)&W[n * 128 + k0 + 4];
            int kt = k0 >> 5, quad = (k0 >> 3) & 3;
            half8 h;
            h[0] = (_Float16)f0.x; h[1] = (_Float16)f0.y;
            h[2] = (_Float16)f0.z; h[3] = (_Float16)f0.w;
            h[4] = (_Float16)f1.x; h[5] = (_Float16)f1.y;
            h[6] = (_Float16)f1.z; h[7] = (_Float16)f1.w;
            *(half8*)&Bf[(size_t)(((kt * 8 + jt) * 4 + quad) * 16 + nlo) * 8] = h;
        }
    }
    __syncthreads();

    const int wave = t >> 6, lane = t & 63;
    const int quad = lane >> 4, nlo = lane & 15;
    const int r0 = blockIdx.x * 64 + wave * 16;
    const int rA = r0 + nlo;
    const int rAc = (rA < N) ? rA : (N - 1);
    const float dv = dinv[rAc];

    float4v acc[8];
#pragma unroll
    for (int j = 0; j < 8; ++j) acc[j] = (float4v){0.f, 0.f, 0.f, 0.f};

#pragma unroll
    for (int kt = 0; kt < 4; ++kt) {
        const float* xp = x + (size_t)rAc * D + kt * 32 + quad * 8;
        float4 a0 = *(const float4*)xp;
        float4 a1 = *(const float4*)(xp + 4);
        half8 va;
        va[0] = (_Float16)(a0.x * dv); va[1] = (_Float16)(a0.y * dv);
        va[2] = (_Float16)(a0.z * dv); va[3] = (_Float16)(a0.w * dv);
        va[4] = (_Float16)(a1.x * dv); va[5] = (_Float16)(a1.y * dv);
        va[6] = (_Float16)(a1.z * dv); va[7] = (_Float16)(a1.w * dv);
#pragma unroll
        for (int jt = 0; jt < 8; ++jt) {
            half8 vb = *(half8*)&Bf[(size_t)((kt * 8 + jt) * 64 + lane) * 8];
            acc[jt] = __builtin_amdgcn_mfma_f32_16x16x32_f16(va, vb, acc[jt], 0, 0, 0);
        }
    }

#pragma unroll
    for (int reg = 0; reg < 4; ++reg) {
        int row = r0 + quad * 4 + reg;
        if (row < N) {
            half8 h;
#pragma unroll
            for (int jt = 0; jt < 8; ++jt) h[jt] = (_Float16)acc[jt][reg];
            *(half8*)((_Float16*)xw + (size_t)row * D + nlo * 8) = h;
        }
    }
}

// ---------------- gather + fused epilogue ----------------
// out[d][c] = x[d][c] + relu(dinv[d]*(xw[d] + sum_e xw[src_e]) + b[c])
// sigma-permuted: lane l's half2 = real cols c0=(l&3)*32+(l>>2), c1=c0+16.
__global__ __launch_bounds__(256) void gather_kernel(const float* __restrict__ x,
                                                     const __half* __restrict__ xw,
                                                     const int* __restrict__ srcs,
                                                     const int* __restrict__ deg,
                                                     const float* __restrict__ dinv,
                                                     const float* __restrict__ bias,
                                                     const int* __restrict__ ovfA_cnt,
                                                     const int2* __restrict__ ovfA,
                                                     const int* __restrict__ ovfB_cnt,
                                                     const int2* __restrict__ ovfB,
                                                     float* __restrict__ out, int N) {
    int node = blockIdx.x * 4 + (threadIdx.x >> 6);
    if (node >= N) return;
    int lane = threadIdx.x & 63;
    int degn = deg[node];
    int end = (degn < CAP) ? degn : CAP;
    float dvd = dinv[node];
    size_t noff = (size_t)node * D;
    const __half2* xw2 = (const __half2*)xw;
    const int* sp = srcs + (size_t)node * CAP;

    float2 fs = __half22float2(xw2[(size_t)node * 64 + lane]);  // self term
    float s0 = fs.x, s1 = fs.y;

    int e = 0;
    for (; e + 7 < end; e += 8) {
        int i0 = sp[e + 0], i1 = sp[e + 1], i2 = sp[e + 2], i3 = sp[e + 3];
        int i4 = sp[e + 4], i5 = sp[e + 5], i6 = sp[e + 6], i7 = sp[e + 7];
        float2 f0 = __half22float2(xw2[(size_t)i0 * 64 + lane]);
        float2 f1 = __half22float2(xw2[(size_t)i1 * 64 + lane]);
        float2 f2 = __half22float2(xw2[(size_t)i2 * 64 + lane]);
        float2 f3 = __half22float2(xw2[(size_t)i3 * 64 + lane]);
        float2 f4 = __half22float2(xw2[(size_t)i4 * 64 + lane]);
        float2 f5 = __half22float2(xw2[(size_t)i5 * 64 + lane]);
        float2 f6 = __half22float2(xw2[(size_t)i6 * 64 + lane]);
        float2 f7 = __half22float2(xw2[(size_t)i7 * 64 + lane]);
        s0 += (f0.x + f1.x) + (f2.x + f3.x) + ((f4.x + f5.x) + (f6.x + f7.x));
        s1 += (f0.y + f1.y) + (f2.y + f3.y) + ((f4.y + f5.y) + (f6.y + f7.y));
    }
    for (; e < end; ++e) {
        float2 f = __half22float2(xw2[(size_t)sp[e] * 64 + lane]);
        s0 += f.x;
        s1 += f.y;
    }

    // spill lists (statistically empty; one uniform load each when empty)
    int na = *ovfA_cnt;
    if (na > 0) {
        if (na > OVF_CAP) na = OVF_CAP;
        for (int k = 0; k < na; ++k) {
            int2 pr = ovfA[k];
            if (pr.x == node) {
                float2 f = __half22float2(xw2[(size_t)pr.y * 64 + lane]);
                s0 += f.x; s1 += f.y;
            }
        }
    }
    int nb2 = *ovfB_cnt;
    if (nb2 > 0) {
        if (nb2 > OVF_CAP) nb2 = OVF_CAP;
        for (int k = 0; k < nb2; ++k) {
            int2 pr = ovfB[k];
            if (pr.x == node) {
                float2 f = __half22float2(xw2[(size_t)pr.y * 64 + lane]);
                s0 += f.x; s1 += f.y;
            }
        }
    }

    int c0 = (lane & 3) * 32 + (lane >> 2);
    int c1 = c0 + 16;
    float h0 = s0 * dvd + bias[c0];
    float h1 = s1 * dvd + bias[c1];
    out[noff + c0] = x[noff + c0] + (h0 > 0.f ? h0 : 0.f);
    out[noff + c1] = x[noff + c1] + (h1 > 0.f ? h1 : 0.f);
}

extern "C" void kernel_launch(void* const* d_in, const int* in_sizes, int n_in,
                              void* d_out, int out_size, void* d_ws, size_t ws_size,
                              hipStream_t stream) {
    const float* x = (const float*)d_in[0];
    const int* ei = (const int*)d_in[1];
    const float* W = (const float*)d_in[2];
    const float* bias = (const float*)d_in[3];
    float* out = (float*)d_out;

    const int N = in_sizes[0] / D;   // 50000
    const int E = in_sizes[1] / 2;   // 1,600,000
    const int* src = ei;
    const int* dst = ei + E;
    const int NB = (N + BSIZE - 1) / BSIZE;  // 782 (<= NBMAX)

    // workspace (~47 MB). pairs dead after bucketB -> xw overlays pairs
    // (12.8 MB <= 19.2 MB).
    char* p = (char*)d_ws;
    int2* pairs = (int2*)p;
    __half* xw = (__half*)p;   p += (size_t)NB * BCAP * sizeof(int2);   // 19.2 MB
    int* deg = (int*)p;        p += (size_t)N * sizeof(int);
    float* dinv = (float*)p;   p += (size_t)N * sizeof(float);
    int* bucket_cnt = (int*)p; p += (size_t)NBMAX * sizeof(int);
    int* ovfA_cnt = (int*)p;
    int* ovfB_cnt = (int*)(p + 16); p += 32;
    int2* ovfA = (int2*)p;     p += (size_t)OVF_CAP * sizeof(int2);     // 0.5 MB
    int2* ovfB = (int2*)p;     p += (size_t)OVF_CAP * sizeof(int2);     // 0.5 MB
    int* ph = (int*)p;         p += (size_t)PA_BLOCKS * NB * sizeof(int); // 0.8 MB
    int* srcs = (int*)p;       p += (size_t)N * CAP * sizeof(int);      // 25.6 MB

    hipMemsetAsync(ovfA_cnt, 0, 32, stream);  // only the two spill counters

    histA_kernel<<<PA_BLOCKS, 256, 0, stream>>>(dst, ph, E, NB);
    scanA_kernel<<<NB, PA_BLOCKS, 0, stream>>>(ph, bucket_cnt, NB);
    placeA_kernel<<<PA_BLOCKS, 256, 0, stream>>>(src, dst, ph, pairs,
                                                 ovfA_cnt, ovfA, E, NB);
    bucketB_kernel<<<NB, 256, 0, stream>>>(pairs, bucket_cnt, srcs, deg,
                                           ovfB_cnt, ovfB, N, NB);
    degfix_kernel<<<1, 256, 0, stream>>>(ovfA_cnt, ovfA, deg);
    dinv_kernel<<<(N + 255) / 256, 256, 0, stream>>>(deg, dinv, N);
    xw_kernel<<<(N + 63) / 64, 256, 0, stream>>>(x, dinv, W, xw, N);
    gather_kernel<<<(N + 3) / 4, 256, 0, stream>>>(x, xw, srcs, deg, dinv, bias,
                                                   ovfA_cnt, ovfA, ovfB_cnt, ovfB,
                                                   out, N);
}